// Round 4
// baseline (1380.776 us; speedup 1.0000x reference)
//
#include <hip/hip_runtime.h>
#include <hip/hip_bf16.h>

#define N_NODES 50000
#define N_EDGES 400000
#define IN_CH   814
#define HID     128
#define HEADS1  4
#define NUM_GRAPHS 64
#define NUM_CLASSES 46
#define NEG_SLOPE 0.2f

__device__ __forceinline__ float leaky(float v) { return v > 0.f ? v : NEG_SLOPE * v; }

// ---------------- fp32 tiled GEMM: C[M,N] = A[M,K] @ B[K,N] ----------------
// BM=BN=128, BK=8, 256 threads, 8x8 per thread (split 4+4 rows/cols for LDS banking)
template<int BM, int BN, int BK>
__global__ __launch_bounds__(256) void gemm_f32(const float* __restrict__ A,
                                                const float* __restrict__ B,
                                                float* __restrict__ C,
                                                int M, int N, int K) {
  __shared__ float sA[BK][BM];
  __shared__ float sB[BK][BN];
  const int tid = threadIdx.x;
  const int brow = blockIdx.x * BM;
  const int bcol = blockIdx.y * BN;
  const int tr4 = (tid >> 4) * 4;   // 0..60
  const int tc4 = (tid & 15) * 4;   // 0..60

  float acc[8][8];
#pragma unroll
  for (int i = 0; i < 8; i++)
#pragma unroll
    for (int j = 0; j < 8; j++) acc[i][j] = 0.f;

  for (int k0 = 0; k0 < K; k0 += BK) {
    // --- stage A tile: 128 rows x 8 k (transposed into k-major LDS) ---
    {
      const int row = tid >> 1;
      const int kb = k0 + ((tid & 1) << 2);
      float av[4] = {0.f, 0.f, 0.f, 0.f};
      const int gr = brow + row;
      if (gr < M) {
        const float* ap = A + (size_t)gr * K + kb;
        if (kb + 3 < K) {
          // rows are 8B-aligned for K=814 -> use float2 pairs
          float2 u0 = *(const float2*)ap;
          float2 u1 = *(const float2*)(ap + 2);
          av[0] = u0.x; av[1] = u0.y; av[2] = u1.x; av[3] = u1.y;
        } else {
#pragma unroll
          for (int i = 0; i < 4; i++) if (kb + i < K) av[i] = ap[i];
        }
      }
      const int kk = (tid & 1) << 2;
#pragma unroll
      for (int i = 0; i < 4; i++) sA[kk + i][row] = av[i];
    }
    // --- stage B tile: 8 k x 128 cols ---
    {
      const int kk = tid >> 5;          // 0..7
      const int col = (tid & 31) * 4;   // 0..124
      float4 v = make_float4(0.f, 0.f, 0.f, 0.f);
      const int gk = k0 + kk;
      if (gk < K) v = *(const float4*)(B + (size_t)gk * N + bcol + col);
      *(float4*)&sB[kk][col] = v;
    }
    __syncthreads();
#pragma unroll
    for (int kk = 0; kk < BK; kk++) {
      float a[8], b[8];
      *(float4*)&a[0] = *(const float4*)&sA[kk][tr4];
      *(float4*)&a[4] = *(const float4*)&sA[kk][tr4 + 64];
      *(float4*)&b[0] = *(const float4*)&sB[kk][tc4];
      *(float4*)&b[4] = *(const float4*)&sB[kk][tc4 + 64];
#pragma unroll
      for (int i = 0; i < 8; i++)
#pragma unroll
        for (int j = 0; j < 8; j++) acc[i][j] += a[i] * b[j];
    }
    __syncthreads();
  }
  // --- store ---
#pragma unroll
  for (int ih = 0; ih < 2; ih++) {
#pragma unroll
    for (int i = 0; i < 4; i++) {
      const int gr = brow + ih * 64 + tr4 + i;
      if (gr < M) {
        float* cp = C + (size_t)gr * N + bcol;
        *(float4*)(cp + tc4)      = *(float4*)&acc[ih * 4 + i][0];
        *(float4*)(cp + tc4 + 64) = *(float4*)&acc[ih * 4 + i][4];
      }
    }
  }
}

// ---------------- attention logit prep, layer 1 (4 heads x 128) ----------------
__global__ __launch_bounds__(256) void attn_prep1(const float* __restrict__ h1,
                                                  const float* __restrict__ a_src,
                                                  const float* __restrict__ a_dst,
                                                  float* __restrict__ als,
                                                  float* __restrict__ ald) {
  const int n = blockIdx.x * 4 + (threadIdx.x >> 6);
  const int lane = threadIdx.x & 63;
  if (n >= N_NODES) return;
  const float* hr = h1 + (size_t)n * 512;
  float ps[4] = {0, 0, 0, 0}, pd[4] = {0, 0, 0, 0};
#pragma unroll
  for (int j = 0; j < 8; j++) {
    const int c = lane + 64 * j;
    const float hv = hr[c];
    ps[j >> 1] += hv * a_src[c];
    pd[j >> 1] += hv * a_dst[c];
  }
#pragma unroll
  for (int off = 32; off; off >>= 1) {
#pragma unroll
    for (int h = 0; h < 4; h++) {
      ps[h] += __shfl_xor(ps[h], off);
      pd[h] += __shfl_xor(pd[h], off);
    }
  }
  if (lane == 0) {
#pragma unroll
    for (int h = 0; h < 4; h++) {
      als[n * 4 + h] = ps[h];
      ald[n * 4 + h] = pd[h];
    }
  }
}

// ---------------- attention logit prep, layer 2 (1 head x 128) ----------------
__global__ __launch_bounds__(256) void attn_prep2(const float* __restrict__ h2,
                                                  const float* __restrict__ a_src,
                                                  const float* __restrict__ a_dst,
                                                  float* __restrict__ als,
                                                  float* __restrict__ ald) {
  const int n = blockIdx.x * 4 + (threadIdx.x >> 6);
  const int lane = threadIdx.x & 63;
  if (n >= N_NODES) return;
  const float* hr = h2 + (size_t)n * 128;
  float h0 = hr[lane], h1v = hr[lane + 64];
  float ps = h0 * a_src[lane] + h1v * a_src[lane + 64];
  float pd = h0 * a_dst[lane] + h1v * a_dst[lane + 64];
#pragma unroll
  for (int off = 32; off; off >>= 1) {
    ps += __shfl_xor(ps, off);
    pd += __shfl_xor(pd, off);
  }
  if (lane == 0) { als[n] = ps; ald[n] = pd; }
}

// ---------------- CSR build ----------------
__global__ void init_misc(int* deg, float* pooled, float* cnts) {
  const int i = blockIdx.x * 256 + threadIdx.x;
  if (i < N_NODES) deg[i] = 1;  // self-loop
  if (i < NUM_GRAPHS * HID) pooled[i] = 0.f;
  if (i < NUM_GRAPHS) cnts[i] = 0.f;
}

__global__ void hist_kernel(const int* __restrict__ dst, int* deg) {
  const int e = blockIdx.x * 256 + threadIdx.x;
  if (e < N_EDGES) atomicAdd(&deg[dst[e]], 1);
}

__global__ __launch_bounds__(1024) void scan_kernel(const int* __restrict__ deg,
                                                    int* offsets, int* cursor) {
  __shared__ int tmp[1024];
  __shared__ int carry;
  const int t = threadIdx.x;
  if (t == 0) carry = 0;
  __syncthreads();
  for (int base = 0; base < N_NODES; base += 1024) {
    const int i = base + t;
    const int v = (i < N_NODES) ? deg[i] : 0;
    tmp[t] = v;
    __syncthreads();
    for (int off = 1; off < 1024; off <<= 1) {
      int add = (t >= off) ? tmp[t - off] : 0;
      __syncthreads();
      tmp[t] += add;
      __syncthreads();
    }
    const int excl = tmp[t] - v;
    if (i < N_NODES) {
      offsets[i] = carry + excl;
      cursor[i] = carry + excl;
    }
    const int total = tmp[1023];
    __syncthreads();
    if (t == 0) carry += total;
    __syncthreads();
  }
  if (t == 0) offsets[N_NODES] = carry;
}

__global__ void scatter_kernel(const int* __restrict__ src, const int* __restrict__ dst,
                               int* cursor, int* __restrict__ srcs) {
  const int e = blockIdx.x * 256 + threadIdx.x;
  if (e >= N_EDGES + N_NODES) return;
  int s, d;
  if (e < N_EDGES) { s = src[e]; d = dst[e]; }
  else { s = e - N_EDGES; d = s; }
  const int p = atomicAdd(&cursor[d], 1);
  srcs[p] = s;
}

// ---------------- GAT aggregation layer 1: one wave per dst node ----------------
__global__ __launch_bounds__(256) void aggregate1(const float* __restrict__ h1,
                                                  const float* __restrict__ als,
                                                  const float* __restrict__ ald,
                                                  const int* __restrict__ offsets,
                                                  const int* __restrict__ srcs,
                                                  const float* __restrict__ b1,
                                                  float* __restrict__ x2) {
  const int n = blockIdx.x * 4 + (threadIdx.x >> 6);
  const int lane = threadIdx.x & 63;
  if (n >= N_NODES) return;
  const int beg = offsets[n], end = offsets[n + 1];
  const float4 aldv = *(const float4*)(ald + (size_t)n * 4);
  // pass 1: per-head max (redundant across lanes; broadcast loads)
  float m0 = -1e30f, m1 = -1e30f, m2 = -1e30f, m3 = -1e30f;
  for (int p = beg; p < end; p++) {
    const int s = srcs[p];
    const float4 as = *(const float4*)(als + (size_t)s * 4);
    m0 = fmaxf(m0, leaky(as.x + aldv.x));
    m1 = fmaxf(m1, leaky(as.y + aldv.y));
    m2 = fmaxf(m2, leaky(as.z + aldv.z));
    m3 = fmaxf(m3, leaky(as.w + aldv.w));
  }
  // pass 2: weighted accumulation (channels c = lane + 64j, head = j>>1)
  float den[4] = {0, 0, 0, 0};
  float acc[8] = {0, 0, 0, 0, 0, 0, 0, 0};
  for (int p = beg; p < end; p++) {
    const int s = srcs[p];
    const float4 as = *(const float4*)(als + (size_t)s * 4);
    float w[4];
    w[0] = __expf(leaky(as.x + aldv.x) - m0);
    w[1] = __expf(leaky(as.y + aldv.y) - m1);
    w[2] = __expf(leaky(as.z + aldv.z) - m2);
    w[3] = __expf(leaky(as.w + aldv.w) - m3);
    den[0] += w[0]; den[1] += w[1]; den[2] += w[2]; den[3] += w[3];
    const float* hr = h1 + (size_t)s * 512;
#pragma unroll
    for (int j = 0; j < 8; j++) acc[j] += w[j >> 1] * hr[lane + 64 * j];
  }
#pragma unroll
  for (int j = 0; j < 8; j++) {
    const int c = lane + 64 * j;
    const float v = acc[j] / den[j >> 1] + b1[c];
    x2[(size_t)n * 512 + c] = fmaxf(v, 0.f);  // relu
  }
}

// ---------------- GAT aggregation layer 2 (1 head, 128 ch) ----------------
__global__ __launch_bounds__(256) void aggregate2(const float* __restrict__ h2,
                                                  const float* __restrict__ als,
                                                  const float* __restrict__ ald,
                                                  const int* __restrict__ offsets,
                                                  const int* __restrict__ srcs,
                                                  const float* __restrict__ b2,
                                                  float* __restrict__ out2) {
  const int n = blockIdx.x * 4 + (threadIdx.x >> 6);
  const int lane = threadIdx.x & 63;
  if (n >= N_NODES) return;
  const int beg = offsets[n], end = offsets[n + 1];
  const float aldn = ald[n];
  float m = -1e30f;
  for (int p = beg; p < end; p++) m = fmaxf(m, leaky(als[srcs[p]] + aldn));
  float den = 0.f, acc0 = 0.f, acc1 = 0.f;
  for (int p = beg; p < end; p++) {
    const int s = srcs[p];
    const float w = __expf(leaky(als[s] + aldn) - m);
    den += w;
    const float* hr = h2 + (size_t)s * 128;
    acc0 += w * hr[lane];
    acc1 += w * hr[lane + 64];
  }
  out2[(size_t)n * 128 + lane]      = fmaxf(acc0 / den + b2[lane], 0.f);
  out2[(size_t)n * 128 + lane + 64] = fmaxf(acc1 / den + b2[lane + 64], 0.f);
}

// ---------------- global mean pool (batch sorted -> run-length accumulate) ----------------
__global__ __launch_bounds__(128) void pool_kernel(const float* __restrict__ out2,
                                                   const int* __restrict__ batch,
                                                   float* pooled, float* cnts) {
  const int t = threadIdx.x;  // channel
  const int base = blockIdx.x * 256;
  float acc = 0.f;
  float cnt = 0.f;
  int cur = -1;
  for (int i = 0; i < 256; i++) {
    const int n = base + i;
    if (n >= N_NODES) break;
    const int g = batch[n];
    if (g != cur) {
      if (cur >= 0) {
        atomicAdd(&pooled[cur * HID + t], acc);
        if (t == 0) atomicAdd(&cnts[cur], cnt);
      }
      acc = 0.f; cnt = 0.f; cur = g;
    }
    acc += out2[(size_t)n * HID + t];
    cnt += 1.f;
  }
  if (cur >= 0) {
    atomicAdd(&pooled[cur * HID + t], acc);
    if (t == 0) atomicAdd(&cnts[cur], cnt);
  }
}

// ---------------- MLP head ----------------
__global__ __launch_bounds__(64) void mlp_kernel(const float* __restrict__ pooled,
                                                 const float* __restrict__ cnts,
                                                 const float* __restrict__ fc1_w,
                                                 const float* __restrict__ fc1_b,
                                                 const float* __restrict__ fc2_w,
                                                 const float* __restrict__ fc2_b,
                                                 float* __restrict__ out) {
  __shared__ float pl[128];
  __shared__ float z[64];
  const int g = blockIdx.x, t = threadIdx.x;
  const float c = fmaxf(cnts[g], 1.0f);
  pl[t] = pooled[g * HID + t] / c;
  pl[t + 64] = pooled[g * HID + t + 64] / c;
  __syncthreads();
  float acc = fc1_b[t];
  for (int i = 0; i < 128; i++) acc += pl[i] * fc1_w[i * 64 + t];
  z[t] = fmaxf(acc, 0.f);
  __syncthreads();
  if (t < NUM_CLASSES) {
    float o = fc2_b[t];
    for (int i = 0; i < 64; i++) o += z[i] * fc2_w[i * NUM_CLASSES + t];
    out[g * NUM_CLASSES + t] = o;
  }
}

extern "C" void kernel_launch(void* const* d_in, const int* in_sizes, int n_in,
                              void* d_out, int out_size, void* d_ws, size_t ws_size,
                              hipStream_t stream) {
  const float* x       = (const float*)d_in[0];
  const int*   ei      = (const int*)d_in[1];
  const int*   batch   = (const int*)d_in[2];
  const float* W1      = (const float*)d_in[3];
  const float* a_src1  = (const float*)d_in[4];
  const float* a_dst1  = (const float*)d_in[5];
  const float* b1      = (const float*)d_in[6];
  const float* W2      = (const float*)d_in[7];
  const float* a_src2  = (const float*)d_in[8];
  const float* a_dst2  = (const float*)d_in[9];
  const float* b2      = (const float*)d_in[10];
  const float* fc1_w   = (const float*)d_in[11];
  const float* fc1_b   = (const float*)d_in[12];
  const float* fc2_w   = (const float*)d_in[13];
  const float* fc2_b   = (const float*)d_in[14];
  float* out = (float*)d_out;

  const int* e_src = ei;
  const int* e_dst = ei + N_EDGES;

  // workspace layout (floats unless noted)
  float* h1   = (float*)d_ws;                 // 25,600,000  (reused: h2 @ h1, out2 @ h1+6.4M)
  float* x2   = h1 + 25600000;                // 25,600,000
  float* als1 = x2 + 25600000;                // 200,000
  float* ald1 = als1 + 200000;                // 200,000
  float* als2 = ald1 + 200000;                // 50,000
  float* ald2 = als2 + 50000;                 // 50,000
  float* pooled = ald2 + 50000;               // 8,192
  float* cnts = pooled + 8192;                // 64
  int* deg    = (int*)(cnts + 64);            // 50,000
  int* offsets = deg + 50000;                 // 50,001
  int* cursor  = offsets + 50001;             // 50,000
  int* srcs    = cursor + 50000;              // 450,000
  float* h2   = h1;                           // 6,400,000 (h1 dead after aggregate1)
  float* out2 = h1 + 6400000;                 // 6,400,000

  // CSR build + inits (independent of GEMM1; launch first)
  init_misc<<<196, 256, 0, stream>>>(deg, pooled, cnts);
  hist_kernel<<<(N_EDGES + 255) / 256, 256, 0, stream>>>(e_dst, deg);
  scan_kernel<<<1, 1024, 0, stream>>>(deg, offsets, cursor);
  scatter_kernel<<<(N_EDGES + N_NODES + 255) / 256, 256, 0, stream>>>(e_src, e_dst, cursor, srcs);

  // layer 1
  gemm_f32<128, 128, 8><<<dim3(391, 4), 256, 0, stream>>>(x, W1, h1, N_NODES, 512, IN_CH);
  attn_prep1<<<12500, 256, 0, stream>>>(h1, a_src1, a_dst1, als1, ald1);
  aggregate1<<<12500, 256, 0, stream>>>(h1, als1, ald1, offsets, srcs, b1, x2);

  // layer 2
  gemm_f32<128, 128, 8><<<dim3(391, 1), 256, 0, stream>>>(x2, W2, h2, N_NODES, HID, 512);
  attn_prep2<<<12500, 256, 0, stream>>>(h2, a_src2, a_dst2, als2, ald2);
  aggregate2<<<12500, 256, 0, stream>>>(h2, als2, ald2, offsets, srcs, b2, out2);

  // pool + MLP
  pool_kernel<<<(N_NODES + 255) / 256, 128, 0, stream>>>(out2, batch, pooled, cnts);
  mlp_kernel<<<NUM_GRAPHS, 64, 0, stream>>>(pooled, cnts, fc1_w, fc1_b, fc2_w, fc2_b, out);
}

// Round 5
// 987.950 us; speedup vs baseline: 1.3976x; 1.3976x over previous
//
#include <hip/hip_runtime.h>
#include <hip/hip_bf16.h>

#define N_NODES 50000
#define N_EDGES 400000
#define IN_CH   814
#define HID     128
#define HEADS1  4
#define NUM_GRAPHS 64
#define NUM_CLASSES 46
#define NEG_SLOPE 0.2f
#define KP 832          // IN_CH padded to multiple of 64
#define KSTEPS (KP/64)  // 13

typedef __attribute__((ext_vector_type(8))) short bf16x8;
typedef __attribute__((ext_vector_type(4))) float f32x4;

__device__ __forceinline__ float leaky(float v) { return v > 0.f ? v : NEG_SLOPE * v; }

__device__ __forceinline__ unsigned short f2bf(float f) {  // RNE bf16
  unsigned u = __float_as_uint(f);
  unsigned r = u + 0x7fff + ((u >> 16) & 1);
  return (unsigned short)(r >> 16);
}

#define GLOAD_LDS16(g, l)                                                        \
  __builtin_amdgcn_global_load_lds((const __attribute__((address_space(1))) unsigned*)(g), \
                                   (__attribute__((address_space(3))) unsigned*)(l), 16, 0, 0)

// ---------------- conversion: x fp32 [M][814] -> Ab bf16 [M][832] (zero-pad) ----------------
__global__ __launch_bounds__(256) void convert_x(const float* __restrict__ x,
                                                 unsigned short* __restrict__ Ab) {
  const int row = blockIdx.x;
  const float* xr = x + (size_t)row * IN_CH;
  unsigned short* ar = Ab + (size_t)row * KP;
  for (int c = threadIdx.x; c < KP; c += 256) {
    const float v = (c < IN_CH) ? xr[c] : 0.f;
    ar[c] = f2bf(v);
  }
}

// ---------------- conversion: W1 fp32 [814][512] -> Bt bf16 [512][832] (transposed, zero-pad) ----
__global__ __launch_bounds__(256) void convert_w1t(const float* __restrict__ W1,
                                                   unsigned short* __restrict__ Bt) {
  const int n = blockIdx.x;  // 0..511 output column
  unsigned short* br = Bt + (size_t)n * KP;
  for (int k = threadIdx.x; k < KP; k += 256) {
    const float v = (k < IN_CH) ? W1[(size_t)k * 512 + n] : 0.f;
    br[k] = f2bf(v);
  }
}

// ---------------- bf16 MFMA GEMM1: h1[M][512] = Ab[M][KP] @ Bt[512][KP]^T ----------------
// 128x128 tile, BK=64, 4 waves (2x2 of 64x64), global_load_lds staging,
// LDS quarter-layout [kg][row][8] so each lane's 8 k-elems are a contiguous b128.
__global__ __launch_bounds__(256) void gemm1_mfma(const unsigned short* __restrict__ Ab,
                                                  const unsigned short* __restrict__ Bt,
                                                  float* __restrict__ C) {
  __shared__ unsigned short sA[8 * 128 * 8];  // 16 KB
  __shared__ unsigned short sB[8 * 128 * 8];  // 16 KB
  const int tid = threadIdx.x;
  const int w = tid >> 6, lane = tid & 63;
  const int row0 = blockIdx.x * 128;
  const int col0 = blockIdx.y * 128;
  const int wr = w >> 1, wc = w & 1;

  f32x4 acc[4][4];
#pragma unroll
  for (int mi = 0; mi < 4; mi++)
#pragma unroll
    for (int nj = 0; nj < 4; nj++) acc[mi][nj] = (f32x4){0.f, 0.f, 0.f, 0.f};

  // staging: tile = 1024 slots of 16B (kg = slot>>7, row = slot&127); 4 calls/wave per operand
  long a_off[4], b_off[4];
  int lds_base[4];
#pragma unroll
  for (int c = 0; c < 4; c++) {
    const int s = (w * 4 + c) * 64 + lane;
    const int kg = s >> 7, r = s & 127;
    int arow = row0 + r; if (arow >= N_NODES) arow = N_NODES - 1;  // clamp (never stored)
    a_off[c] = (long)arow * KP + kg * 8;
    b_off[c] = (long)(col0 + r) * KP + kg * 8;
    lds_base[c] = (w * 4 + c) * 64 * 8;  // shorts
  }
  // fragment read offsets (shorts)
  int aoff[4][2], boff[4][2];
#pragma unroll
  for (int i = 0; i < 4; i++)
#pragma unroll
    for (int ks = 0; ks < 2; ks++) {
      aoff[i][ks] = ((ks * 4 + (lane >> 4)) * 128 + wr * 64 + i * 16 + (lane & 15)) * 8;
      boff[i][ks] = ((ks * 4 + (lane >> 4)) * 128 + wc * 64 + i * 16 + (lane & 15)) * 8;
    }

  for (int kt = 0; kt < KSTEPS; ++kt) {
    const int kbase = kt * 64;
#pragma unroll
    for (int c = 0; c < 4; c++) {
      GLOAD_LDS16(Ab + (a_off[c] + kbase), &sA[lds_base[c]]);
      GLOAD_LDS16(Bt + (b_off[c] + kbase), &sB[lds_base[c]]);
    }
    __syncthreads();
    bf16x8 af[4][2], bfr[4][2];
#pragma unroll
    for (int mi = 0; mi < 4; mi++)
#pragma unroll
      for (int ks = 0; ks < 2; ks++) af[mi][ks] = *(const bf16x8*)&sA[aoff[mi][ks]];
#pragma unroll
    for (int nj = 0; nj < 4; nj++)
#pragma unroll
      for (int ks = 0; ks < 2; ks++) bfr[nj][ks] = *(const bf16x8*)&sB[boff[nj][ks]];
#pragma unroll
    for (int mi = 0; mi < 4; mi++)
#pragma unroll
      for (int nj = 0; nj < 4; nj++) {
        acc[mi][nj] = __builtin_amdgcn_mfma_f32_16x16x32_bf16(af[mi][0], bfr[nj][0], acc[mi][nj], 0, 0, 0);
        acc[mi][nj] = __builtin_amdgcn_mfma_f32_16x16x32_bf16(af[mi][1], bfr[nj][1], acc[mi][nj], 0, 0, 0);
      }
    __syncthreads();
  }
  // store: D col = lane&15, row = (lane>>4)*4 + reg  [m89/m91 verified mapping]
  const int r4 = (lane >> 4) * 4;
  const int cc = lane & 15;
#pragma unroll
  for (int mi = 0; mi < 4; mi++) {
#pragma unroll
    for (int r = 0; r < 4; r++) {
      const int gr = row0 + wr * 64 + mi * 16 + r4 + r;
      if (gr < N_NODES) {
        float* cp = C + (size_t)gr * 512 + col0 + wc * 64 + cc;
#pragma unroll
        for (int nj = 0; nj < 4; nj++) cp[nj * 16] = acc[mi][nj][r];
      }
    }
  }
}

// ---------------- fp32 tiled GEMM (layer 2): C[M,N] = A[M,K] @ B[K,N] ----------------
template<int BM, int BN, int BK>
__global__ __launch_bounds__(256) void gemm_f32(const float* __restrict__ A,
                                                const float* __restrict__ B,
                                                float* __restrict__ C,
                                                int M, int N, int K) {
  __shared__ float sA[BK][BM];
  __shared__ float sB[BK][BN];
  const int tid = threadIdx.x;
  const int brow = blockIdx.x * BM;
  const int bcol = blockIdx.y * BN;
  const int tr4 = (tid >> 4) * 4;
  const int tc4 = (tid & 15) * 4;

  float acc[8][8];
#pragma unroll
  for (int i = 0; i < 8; i++)
#pragma unroll
    for (int j = 0; j < 8; j++) acc[i][j] = 0.f;

  for (int k0 = 0; k0 < K; k0 += BK) {
    {
      const int row = tid >> 1;
      const int kb = k0 + ((tid & 1) << 2);
      float av[4] = {0.f, 0.f, 0.f, 0.f};
      const int gr = brow + row;
      if (gr < M) {
        const float* ap = A + (size_t)gr * K + kb;
        if (kb + 3 < K) {
          float2 u0 = *(const float2*)ap;
          float2 u1 = *(const float2*)(ap + 2);
          av[0] = u0.x; av[1] = u0.y; av[2] = u1.x; av[3] = u1.y;
        } else {
#pragma unroll
          for (int i = 0; i < 4; i++) if (kb + i < K) av[i] = ap[i];
        }
      }
      const int kk = (tid & 1) << 2;
#pragma unroll
      for (int i = 0; i < 4; i++) sA[kk + i][row] = av[i];
    }
    {
      const int kk = tid >> 5;
      const int col = (tid & 31) * 4;
      float4 v = make_float4(0.f, 0.f, 0.f, 0.f);
      const int gk = k0 + kk;
      if (gk < K) v = *(const float4*)(B + (size_t)gk * N + bcol + col);
      *(float4*)&sB[kk][col] = v;
    }
    __syncthreads();
#pragma unroll
    for (int kk = 0; kk < BK; kk++) {
      float a[8], b[8];
      *(float4*)&a[0] = *(const float4*)&sA[kk][tr4];
      *(float4*)&a[4] = *(const float4*)&sA[kk][tr4 + 64];
      *(float4*)&b[0] = *(const float4*)&sB[kk][tc4];
      *(float4*)&b[4] = *(const float4*)&sB[kk][tc4 + 64];
#pragma unroll
      for (int i = 0; i < 8; i++)
#pragma unroll
        for (int j = 0; j < 8; j++) acc[i][j] += a[i] * b[j];
    }
    __syncthreads();
  }
#pragma unroll
  for (int ih = 0; ih < 2; ih++) {
#pragma unroll
    for (int i = 0; i < 4; i++) {
      const int gr = brow + ih * 64 + tr4 + i;
      if (gr < M) {
        float* cp = C + (size_t)gr * N + bcol;
        *(float4*)(cp + tc4)      = *(float4*)&acc[ih * 4 + i][0];
        *(float4*)(cp + tc4 + 64) = *(float4*)&acc[ih * 4 + i][4];
      }
    }
  }
}

// ---------------- attention logit prep, layer 1 ----------------
__global__ __launch_bounds__(256) void attn_prep1(const float* __restrict__ h1,
                                                  const float* __restrict__ a_src,
                                                  const float* __restrict__ a_dst,
                                                  float* __restrict__ als,
                                                  float* __restrict__ ald) {
  const int n = blockIdx.x * 4 + (threadIdx.x >> 6);
  const int lane = threadIdx.x & 63;
  if (n >= N_NODES) return;
  const float* hr = h1 + (size_t)n * 512;
  float ps[4] = {0, 0, 0, 0}, pd[4] = {0, 0, 0, 0};
#pragma unroll
  for (int j = 0; j < 8; j++) {
    const int c = lane + 64 * j;
    const float hv = hr[c];
    ps[j >> 1] += hv * a_src[c];
    pd[j >> 1] += hv * a_dst[c];
  }
#pragma unroll
  for (int off = 32; off; off >>= 1) {
#pragma unroll
    for (int h = 0; h < 4; h++) {
      ps[h] += __shfl_xor(ps[h], off);
      pd[h] += __shfl_xor(pd[h], off);
    }
  }
  if (lane == 0) {
#pragma unroll
    for (int h = 0; h < 4; h++) {
      als[n * 4 + h] = ps[h];
      ald[n * 4 + h] = pd[h];
    }
  }
}

// ---------------- attention logit prep, layer 2 ----------------
__global__ __launch_bounds__(256) void attn_prep2(const float* __restrict__ h2,
                                                  const float* __restrict__ a_src,
                                                  const float* __restrict__ a_dst,
                                                  float* __restrict__ als,
                                                  float* __restrict__ ald) {
  const int n = blockIdx.x * 4 + (threadIdx.x >> 6);
  const int lane = threadIdx.x & 63;
  if (n >= N_NODES) return;
  const float* hr = h2 + (size_t)n * 128;
  float h0 = hr[lane], h1v = hr[lane + 64];
  float ps = h0 * a_src[lane] + h1v * a_src[lane + 64];
  float pd = h0 * a_dst[lane] + h1v * a_dst[lane + 64];
#pragma unroll
  for (int off = 32; off; off >>= 1) {
    ps += __shfl_xor(ps, off);
    pd += __shfl_xor(pd, off);
  }
  if (lane == 0) { als[n] = ps; ald[n] = pd; }
}

// ---------------- CSR build ----------------
__global__ void init_misc(int* deg, float* pooled, float* cnts) {
  const int i = blockIdx.x * 256 + threadIdx.x;
  if (i < N_NODES) deg[i] = 1;  // self-loop
  if (i < NUM_GRAPHS * HID) pooled[i] = 0.f;
  if (i < NUM_GRAPHS) cnts[i] = 0.f;
}

__global__ void hist_kernel(const int* __restrict__ dst, int* deg) {
  const int e = blockIdx.x * 256 + threadIdx.x;
  if (e < N_EDGES) atomicAdd(&deg[dst[e]], 1);
}

__global__ __launch_bounds__(1024) void scan_kernel(const int* __restrict__ deg,
                                                    int* offsets, int* cursor) {
  __shared__ int tmp[1024];
  __shared__ int carry;
  const int t = threadIdx.x;
  if (t == 0) carry = 0;
  __syncthreads();
  for (int base = 0; base < N_NODES; base += 1024) {
    const int i = base + t;
    const int v = (i < N_NODES) ? deg[i] : 0;
    tmp[t] = v;
    __syncthreads();
    for (int off = 1; off < 1024; off <<= 1) {
      int add = (t >= off) ? tmp[t - off] : 0;
      __syncthreads();
      tmp[t] += add;
      __syncthreads();
    }
    const int excl = tmp[t] - v;
    if (i < N_NODES) {
      offsets[i] = carry + excl;
      cursor[i] = carry + excl;
    }
    const int total = tmp[1023];
    __syncthreads();
    if (t == 0) carry += total;
    __syncthreads();
  }
  if (t == 0) offsets[N_NODES] = carry;
}

__global__ void scatter_kernel(const int* __restrict__ src, const int* __restrict__ dst,
                               int* cursor, int* __restrict__ srcs) {
  const int e = blockIdx.x * 256 + threadIdx.x;
  if (e >= N_EDGES + N_NODES) return;
  int s, d;
  if (e < N_EDGES) { s = src[e]; d = dst[e]; }
  else { s = e - N_EDGES; d = s; }
  const int p = atomicAdd(&cursor[d], 1);
  srcs[p] = s;
}

// ---------------- GAT aggregation layer 1 ----------------
__global__ __launch_bounds__(256) void aggregate1(const float* __restrict__ h1,
                                                  const float* __restrict__ als,
                                                  const float* __restrict__ ald,
                                                  const int* __restrict__ offsets,
                                                  const int* __restrict__ srcs,
                                                  const float* __restrict__ b1,
                                                  float* __restrict__ x2) {
  const int n = blockIdx.x * 4 + (threadIdx.x >> 6);
  const int lane = threadIdx.x & 63;
  if (n >= N_NODES) return;
  const int beg = offsets[n], end = offsets[n + 1];
  const float4 aldv = *(const float4*)(ald + (size_t)n * 4);
  float m0 = -1e30f, m1 = -1e30f, m2 = -1e30f, m3 = -1e30f;
  for (int p = beg; p < end; p++) {
    const int s = srcs[p];
    const float4 as = *(const float4*)(als + (size_t)s * 4);
    m0 = fmaxf(m0, leaky(as.x + aldv.x));
    m1 = fmaxf(m1, leaky(as.y + aldv.y));
    m2 = fmaxf(m2, leaky(as.z + aldv.z));
    m3 = fmaxf(m3, leaky(as.w + aldv.w));
  }
  float den[4] = {0, 0, 0, 0};
  float acc[8] = {0, 0, 0, 0, 0, 0, 0, 0};
  for (int p = beg; p < end; p++) {
    const int s = srcs[p];
    const float4 as = *(const float4*)(als + (size_t)s * 4);
    float wgt[4];
    wgt[0] = __expf(leaky(as.x + aldv.x) - m0);
    wgt[1] = __expf(leaky(as.y + aldv.y) - m1);
    wgt[2] = __expf(leaky(as.z + aldv.z) - m2);
    wgt[3] = __expf(leaky(as.w + aldv.w) - m3);
    den[0] += wgt[0]; den[1] += wgt[1]; den[2] += wgt[2]; den[3] += wgt[3];
    const float* hr = h1 + (size_t)s * 512;
#pragma unroll
    for (int j = 0; j < 8; j++) acc[j] += wgt[j >> 1] * hr[lane + 64 * j];
  }
#pragma unroll
  for (int j = 0; j < 8; j++) {
    const int c = lane + 64 * j;
    const float v = acc[j] / den[j >> 1] + b1[c];
    x2[(size_t)n * 512 + c] = fmaxf(v, 0.f);
  }
}

// ---------------- GAT aggregation layer 2 ----------------
__global__ __launch_bounds__(256) void aggregate2(const float* __restrict__ h2,
                                                  const float* __restrict__ als,
                                                  const float* __restrict__ ald,
                                                  const int* __restrict__ offsets,
                                                  const int* __restrict__ srcs,
                                                  const float* __restrict__ b2,
                                                  float* __restrict__ out2) {
  const int n = blockIdx.x * 4 + (threadIdx.x >> 6);
  const int lane = threadIdx.x & 63;
  if (n >= N_NODES) return;
  const int beg = offsets[n], end = offsets[n + 1];
  const float aldn = ald[n];
  float m = -1e30f;
  for (int p = beg; p < end; p++) m = fmaxf(m, leaky(als[srcs[p]] + aldn));
  float den = 0.f, acc0 = 0.f, acc1 = 0.f;
  for (int p = beg; p < end; p++) {
    const int s = srcs[p];
    const float w = __expf(leaky(als[s] + aldn) - m);
    den += w;
    const float* hr = h2 + (size_t)s * 128;
    acc0 += w * hr[lane];
    acc1 += w * hr[lane + 64];
  }
  out2[(size_t)n * 128 + lane]      = fmaxf(acc0 / den + b2[lane], 0.f);
  out2[(size_t)n * 128 + lane + 64] = fmaxf(acc1 / den + b2[lane + 64], 0.f);
}

// ---------------- global mean pool ----------------
__global__ __launch_bounds__(128) void pool_kernel(const float* __restrict__ out2,
                                                   const int* __restrict__ batch,
                                                   float* pooled, float* cnts) {
  const int t = threadIdx.x;
  const int base = blockIdx.x * 256;
  float acc = 0.f;
  float cnt = 0.f;
  int cur = -1;
  for (int i = 0; i < 256; i++) {
    const int n = base + i;
    if (n >= N_NODES) break;
    const int g = batch[n];
    if (g != cur) {
      if (cur >= 0) {
        atomicAdd(&pooled[cur * HID + t], acc);
        if (t == 0) atomicAdd(&cnts[cur], cnt);
      }
      acc = 0.f; cnt = 0.f; cur = g;
    }
    acc += out2[(size_t)n * HID + t];
    cnt += 1.f;
  }
  if (cur >= 0) {
    atomicAdd(&pooled[cur * HID + t], acc);
    if (t == 0) atomicAdd(&cnts[cur], cnt);
  }
}

// ---------------- MLP head ----------------
__global__ __launch_bounds__(64) void mlp_kernel(const float* __restrict__ pooled,
                                                 const float* __restrict__ cnts,
                                                 const float* __restrict__ fc1_w,
                                                 const float* __restrict__ fc1_b,
                                                 const float* __restrict__ fc2_w,
                                                 const float* __restrict__ fc2_b,
                                                 float* __restrict__ out) {
  __shared__ float pl[128];
  __shared__ float z[64];
  const int g = blockIdx.x, t = threadIdx.x;
  const float c = fmaxf(cnts[g], 1.0f);
  pl[t] = pooled[g * HID + t] / c;
  pl[t + 64] = pooled[g * HID + t + 64] / c;
  __syncthreads();
  float acc = fc1_b[t];
  for (int i = 0; i < 128; i++) acc += pl[i] * fc1_w[i * 64 + t];
  z[t] = fmaxf(acc, 0.f);
  __syncthreads();
  if (t < NUM_CLASSES) {
    float o = fc2_b[t];
    for (int i = 0; i < 64; i++) o += z[i] * fc2_w[i * NUM_CLASSES + t];
    out[g * NUM_CLASSES + t] = o;
  }
}

extern "C" void kernel_launch(void* const* d_in, const int* in_sizes, int n_in,
                              void* d_out, int out_size, void* d_ws, size_t ws_size,
                              hipStream_t stream) {
  const float* x       = (const float*)d_in[0];
  const int*   ei      = (const int*)d_in[1];
  const int*   batch   = (const int*)d_in[2];
  const float* W1      = (const float*)d_in[3];
  const float* a_src1  = (const float*)d_in[4];
  const float* a_dst1  = (const float*)d_in[5];
  const float* b1      = (const float*)d_in[6];
  const float* W2      = (const float*)d_in[7];
  const float* a_src2  = (const float*)d_in[8];
  const float* a_dst2  = (const float*)d_in[9];
  const float* b2      = (const float*)d_in[10];
  const float* fc1_w   = (const float*)d_in[11];
  const float* fc1_b   = (const float*)d_in[12];
  const float* fc2_w   = (const float*)d_in[13];
  const float* fc2_b   = (const float*)d_in[14];
  float* out = (float*)d_out;

  const int* e_src = ei;
  const int* e_dst = ei + N_EDGES;

  // workspace layout (floats unless noted)
  float* h1   = (float*)d_ws;                 // 25,600,000  [50000][512]
  float* x2   = h1 + 25600000;                // 25,600,000  (Ab/Bt live here until aggregate1)
  float* als1 = x2 + 25600000;                // 200,000
  float* ald1 = als1 + 200000;                // 200,000
  float* als2 = ald1 + 200000;                // 50,000
  float* ald2 = als2 + 50000;                 // 50,000
  float* pooled = ald2 + 50000;               // 8,192
  float* cnts = pooled + 8192;                // 64
  int* deg    = (int*)(cnts + 64);            // 50,000
  int* offsets = deg + 50000;                 // 50,001
  int* cursor  = offsets + 50001;             // 50,000
  int* srcs    = cursor + 50000;              // 450,000
  float* h2   = h1;                           // layer-2 reuse (h1 dead after aggregate1)
  float* out2 = h1 + 6400000;
  // bf16 staging inside x2 region (x2 written only later by aggregate1):
  unsigned short* Ab = (unsigned short*)x2;                    // 50000*832 bf16 = 41.6M shorts (20.8M floats)
  unsigned short* Bt = (unsigned short*)(x2 + 21000000);       // 512*832 bf16

  // CSR build + inits
  init_misc<<<196, 256, 0, stream>>>(deg, pooled, cnts);
  hist_kernel<<<(N_EDGES + 255) / 256, 256, 0, stream>>>(e_dst, deg);
  scan_kernel<<<1, 1024, 0, stream>>>(deg, offsets, cursor);
  scatter_kernel<<<(N_EDGES + N_NODES + 255) / 256, 256, 0, stream>>>(e_src, e_dst, cursor, srcs);

  // layer 1: bf16 conversion + MFMA GEMM
  convert_x<<<N_NODES, 256, 0, stream>>>(x, Ab);
  convert_w1t<<<512, 256, 0, stream>>>(W1, Bt);
  gemm1_mfma<<<dim3(391, 4), 256, 0, stream>>>(Ab, Bt, h1);
  attn_prep1<<<12500, 256, 0, stream>>>(h1, a_src1, a_dst1, als1, ald1);
  aggregate1<<<12500, 256, 0, stream>>>(h1, als1, ald1, offsets, srcs, b1, x2);

  // layer 2 (fp32)
  gemm_f32<128, 128, 8><<<dim3(391, 1), 256, 0, stream>>>(x2, W2, h2, N_NODES, HID, 512);
  attn_prep2<<<12500, 256, 0, stream>>>(h2, a_src2, a_dst2, als2, ald2);
  aggregate2<<<12500, 256, 0, stream>>>(h2, als2, ald2, offsets, srcs, b2, out2);

  // pool + MLP
  pool_kernel<<<(N_NODES + 255) / 256, 128, 0, stream>>>(out2, batch, pooled, cnts);
  mlp_kernel<<<NUM_GRAPHS, 64, 0, stream>>>(pooled, cnts, fc1_w, fc1_b, fc2_w, fc2_b, out);
}

// Round 7
// 731.602 us; speedup vs baseline: 1.8873x; 1.3504x over previous
//
#include <hip/hip_runtime.h>
#include <hip/hip_bf16.h>

#define N_NODES 50000
#define N_EDGES 400000
#define IN_CH   814
#define HID     128
#define HEADS1  4
#define NUM_GRAPHS 64
#define NUM_CLASSES 46
#define NEG_SLOPE 0.2f
#define KP 832          // IN_CH padded to multiple of 64

typedef __attribute__((ext_vector_type(8))) short bf16x8;
typedef __attribute__((ext_vector_type(4))) float f32x4;

__device__ __forceinline__ float leaky(float v) { return v > 0.f ? v : NEG_SLOPE * v; }

__device__ __forceinline__ unsigned short f2bf(float f) {  // RNE bf16
  unsigned u = __float_as_uint(f);
  unsigned r = u + 0x7fff + ((u >> 16) & 1);
  return (unsigned short)(r >> 16);
}
__device__ __forceinline__ float bf2f(short s) {
  return __uint_as_float(((unsigned)(unsigned short)s) << 16);
}

#define GLOAD_LDS16(g, l)                                                        \
  __builtin_amdgcn_global_load_lds((const __attribute__((address_space(1))) unsigned*)(g), \
                                   (__attribute__((address_space(3))) unsigned*)(l), 16, 0, 0)

// ---------------- conversion: x fp32 [M][814] -> Ab bf16 [M][832] (zero-pad) ----------------
__global__ __launch_bounds__(256) void convert_x(const float* __restrict__ x,
                                                 unsigned short* __restrict__ Ab) {
  const int row = blockIdx.x;
  const int c = threadIdx.x * 4;
  if (c >= KP) return;
  const float* xr = x + (size_t)row * IN_CH;
  float v[4] = {0.f, 0.f, 0.f, 0.f};
  if (c + 3 < IN_CH) {  // row base is 8B-aligned (814*4B); use float2 pairs
    float2 u0 = *(const float2*)(xr + c);
    float2 u1 = *(const float2*)(xr + c + 2);
    v[0] = u0.x; v[1] = u0.y; v[2] = u1.x; v[3] = u1.y;
  } else {
#pragma unroll
    for (int k = 0; k < 4; k++) if (c + k < IN_CH) v[k] = xr[c + k];
  }
  ushort4 o = make_ushort4(f2bf(v[0]), f2bf(v[1]), f2bf(v[2]), f2bf(v[3]));
  *(ushort4*)&Ab[(size_t)row * KP + c] = o;
}

// ---------------- W1 fp32 [814][512] -> Bt bf16 [512][832] (transposed, zero-pad) ----------------
__global__ __launch_bounds__(256) void convert_w1t(const float* __restrict__ W1,
                                                   unsigned short* __restrict__ Bt) {
  const int n = blockIdx.x;  // output column 0..511
  unsigned short* br = Bt + (size_t)n * KP;
  for (int k = threadIdx.x; k < KP; k += 256) {
    const float v = (k < IN_CH) ? W1[(size_t)k * 512 + n] : 0.f;
    br[k] = f2bf(v);
  }
}

// ---------------- W2 fp32 [512][128] -> Bt2 bf16 [128][512] (transposed) ----------------
__global__ __launch_bounds__(256) void convert_w2t(const float* __restrict__ W2,
                                                   unsigned short* __restrict__ Bt2) {
  const int n = blockIdx.x;  // output column 0..127
  unsigned short* br = Bt2 + (size_t)n * 512;
  for (int k = threadIdx.x; k < 512; k += 256) br[k] = f2bf(W2[(size_t)k * 128 + n]);
}

// ---------------- bf16 MFMA GEMM: C[M][CPITCH] = A[M][KPITCH] @ B[N][KPITCH]^T ----------------
// 128x128 tile, BK=64, 4 waves (2x2 of 64x64), global_load_lds staging.
template<int KPITCH, int CPITCH, bool OUTBF>
__global__ __launch_bounds__(256) void gemm_mfma(const unsigned short* __restrict__ A,
                                                 const unsigned short* __restrict__ B,
                                                 void* __restrict__ Cv) {
  __shared__ unsigned short sA[8 * 128 * 8];  // 16 KB
  __shared__ unsigned short sB[8 * 128 * 8];  // 16 KB
  const int tid = threadIdx.x;
  const int w = tid >> 6, lane = tid & 63;
  const int row0 = blockIdx.x * 128;
  const int col0 = blockIdx.y * 128;
  const int wr = w >> 1, wc = w & 1;

  f32x4 acc[4][4];
#pragma unroll
  for (int mi = 0; mi < 4; mi++)
#pragma unroll
    for (int nj = 0; nj < 4; nj++) acc[mi][nj] = (f32x4){0.f, 0.f, 0.f, 0.f};

  long a_off[4], b_off[4];
  int lds_base[4];
#pragma unroll
  for (int c = 0; c < 4; c++) {
    const int s = (w * 4 + c) * 64 + lane;
    const int kg = s >> 7, r = s & 127;
    int arow = row0 + r; if (arow >= N_NODES) arow = N_NODES - 1;  // clamp (never stored)
    a_off[c] = (long)arow * KPITCH + kg * 8;
    b_off[c] = (long)(col0 + r) * KPITCH + kg * 8;
    lds_base[c] = (w * 4 + c) * 64 * 8;  // shorts
  }
  int aoff[4][2], boff[4][2];
#pragma unroll
  for (int i = 0; i < 4; i++)
#pragma unroll
    for (int ks = 0; ks < 2; ks++) {
      aoff[i][ks] = ((ks * 4 + (lane >> 4)) * 128 + wr * 64 + i * 16 + (lane & 15)) * 8;
      boff[i][ks] = ((ks * 4 + (lane >> 4)) * 128 + wc * 64 + i * 16 + (lane & 15)) * 8;
    }

  for (int kt = 0; kt < KPITCH / 64; ++kt) {
    const int kbase = kt * 64;
#pragma unroll
    for (int c = 0; c < 4; c++) {
      GLOAD_LDS16(A + (a_off[c] + kbase), &sA[lds_base[c]]);
      GLOAD_LDS16(B + (b_off[c] + kbase), &sB[lds_base[c]]);
    }
    __syncthreads();
    bf16x8 af[4][2], bfr[4][2];
#pragma unroll
    for (int mi = 0; mi < 4; mi++)
#pragma unroll
      for (int ks = 0; ks < 2; ks++) af[mi][ks] = *(const bf16x8*)&sA[aoff[mi][ks]];
#pragma unroll
    for (int nj = 0; nj < 4; nj++)
#pragma unroll
      for (int ks = 0; ks < 2; ks++) bfr[nj][ks] = *(const bf16x8*)&sB[boff[nj][ks]];
#pragma unroll
    for (int mi = 0; mi < 4; mi++)
#pragma unroll
      for (int nj = 0; nj < 4; nj++) {
        acc[mi][nj] = __builtin_amdgcn_mfma_f32_16x16x32_bf16(af[mi][0], bfr[nj][0], acc[mi][nj], 0, 0, 0);
        acc[mi][nj] = __builtin_amdgcn_mfma_f32_16x16x32_bf16(af[mi][1], bfr[nj][1], acc[mi][nj], 0, 0, 0);
      }
    __syncthreads();
  }
  // store: D col = lane&15, row = (lane>>4)*4 + reg  [HW-verified round 4/5]
  const int r4 = (lane >> 4) * 4;
  const int cc = lane & 15;
#pragma unroll
  for (int mi = 0; mi < 4; mi++) {
#pragma unroll
    for (int r = 0; r < 4; r++) {
      const int gr = row0 + wr * 64 + mi * 16 + r4 + r;
      if (gr < N_NODES) {
        if (OUTBF) {
          unsigned short* cp = (unsigned short*)Cv + (size_t)gr * CPITCH + col0 + wc * 64 + cc;
#pragma unroll
          for (int nj = 0; nj < 4; nj++) cp[nj * 16] = f2bf(acc[mi][nj][r]);
        } else {
          float* cp = (float*)Cv + (size_t)gr * CPITCH + col0 + wc * 64 + cc;
#pragma unroll
          for (int nj = 0; nj < 4; nj++) cp[nj * 16] = acc[mi][nj][r];
        }
      }
    }
  }
}

// ---------------- attention logit prep, layer 1 (h1 bf16; lane owns 8 contiguous ch) ----------------
__global__ __launch_bounds__(256) void attn_prep1(const unsigned short* __restrict__ h1b,
                                                  const float* __restrict__ a_src,
                                                  const float* __restrict__ a_dst,
                                                  float* __restrict__ als,
                                                  float* __restrict__ ald) {
  const int n = blockIdx.x * 4 + (threadIdx.x >> 6);
  const int lane = threadIdx.x & 63;
  if (n >= N_NODES) return;
  const int c0 = lane * 8;                 // head = lane>>4 (8 ch never straddle 128)
  const bf16x8 hv = *(const bf16x8*)&h1b[(size_t)n * 512 + c0];
  float ps = 0.f, pd = 0.f;
#pragma unroll
  for (int j = 0; j < 8; j++) {
    const float f = bf2f(hv[j]);
    ps += f * a_src[c0 + j];
    pd += f * a_dst[c0 + j];
  }
#pragma unroll
  for (int off = 8; off; off >>= 1) {      // reduce within 16-lane head group
    ps += __shfl_xor(ps, off);
    pd += __shfl_xor(pd, off);
  }
  if ((lane & 15) == 0) {
    als[n * 4 + (lane >> 4)] = ps;
    ald[n * 4 + (lane >> 4)] = pd;
  }
}

// ---------------- attention logit prep, layer 2 (h2 fp32, 1 head) ----------------
__global__ __launch_bounds__(256) void attn_prep2(const float* __restrict__ h2,
                                                  const float* __restrict__ a_src,
                                                  const float* __restrict__ a_dst,
                                                  float* __restrict__ als,
                                                  float* __restrict__ ald) {
  const int n = blockIdx.x * 4 + (threadIdx.x >> 6);
  const int lane = threadIdx.x & 63;
  if (n >= N_NODES) return;
  const float* hr = h2 + (size_t)n * 128;
  float h0 = hr[lane], h1v = hr[lane + 64];
  float ps = h0 * a_src[lane] + h1v * a_src[lane + 64];
  float pd = h0 * a_dst[lane] + h1v * a_dst[lane + 64];
#pragma unroll
  for (int off = 32; off; off >>= 1) {
    ps += __shfl_xor(ps, off);
    pd += __shfl_xor(pd, off);
  }
  if (lane == 0) { als[n] = ps; ald[n] = pd; }
}

// ---------------- CSR build ----------------
__global__ void init_misc(int* deg, float* pooled, float* cnts) {
  const int i = blockIdx.x * 256 + threadIdx.x;
  if (i < N_NODES) deg[i] = 1;  // self-loop
  if (i < NUM_GRAPHS * HID) pooled[i] = 0.f;
  if (i < NUM_GRAPHS) cnts[i] = 0.f;
}

__global__ void hist_kernel(const int* __restrict__ dst, int* deg) {
  const int e = blockIdx.x * 256 + threadIdx.x;
  if (e < N_EDGES) atomicAdd(&deg[dst[e]], 1);
}

// two-level scan (replaces 1000-barrier single-block scan)
__global__ __launch_bounds__(256) void scan_block_sum(const int* __restrict__ deg, int* bsum) {
  __shared__ int sd[256];
  const int t = threadIdx.x;
  const int i = blockIdx.x * 256 + t;
  sd[t] = (i < N_NODES) ? deg[i] : 0;
  __syncthreads();
  for (int s = 128; s; s >>= 1) { if (t < s) sd[t] += sd[t + s]; __syncthreads(); }
  if (t == 0) bsum[blockIdx.x] = sd[0];
}

__global__ __launch_bounds__(256) void scan_base(const int* __restrict__ bsum, int* bbase, int* offsets) {
  __shared__ int tmp[256];
  const int t = threadIdx.x;
  const int nb = (N_NODES + 255) / 256;
  const int v = (t < nb) ? bsum[t] : 0;
  tmp[t] = v;
  __syncthreads();
  for (int off = 1; off < 256; off <<= 1) {
    int a = (t >= off) ? tmp[t - off] : 0;
    __syncthreads();
    tmp[t] += a;
    __syncthreads();
  }
  if (t < nb) bbase[t] = tmp[t] - v;
  if (t == 255) offsets[N_NODES] = tmp[255];
}

__global__ __launch_bounds__(256) void scan_final(const int* __restrict__ deg,
                                                  const int* __restrict__ bbase,
                                                  int* offsets, int* cursor) {
  __shared__ int tmp[256];
  const int t = threadIdx.x;
  const int i = blockIdx.x * 256 + t;
  const int v = (i < N_NODES) ? deg[i] : 0;
  tmp[t] = v;
  __syncthreads();
  for (int off = 1; off < 256; off <<= 1) {
    int a = (t >= off) ? tmp[t - off] : 0;
    __syncthreads();
    tmp[t] += a;
    __syncthreads();
  }
  if (i < N_NODES) {
    const int excl = bbase[blockIdx.x] + tmp[t] - v;
    offsets[i] = excl;
    cursor[i] = excl;
  }
}

__global__ void scatter_kernel(const int* __restrict__ src, const int* __restrict__ dst,
                               int* cursor, int* __restrict__ srcs) {
  const int e = blockIdx.x * 256 + threadIdx.x;
  if (e >= N_EDGES + N_NODES) return;
  int s, d;
  if (e < N_EDGES) { s = src[e]; d = dst[e]; }
  else { s = e - N_EDGES; d = s; }
  const int p = atomicAdd(&cursor[d], 1);
  srcs[p] = s;
}

// ---------------- GAT aggregation layer 1 (bf16 in/out; lane owns 8 contiguous ch) ----------------
__global__ __launch_bounds__(256) void aggregate1(const unsigned short* __restrict__ h1b,
                                                  const float* __restrict__ als,
                                                  const float* __restrict__ ald,
                                                  const int* __restrict__ offsets,
                                                  const int* __restrict__ srcs,
                                                  const float* __restrict__ b1,
                                                  unsigned short* __restrict__ x2b) {
  const int n = blockIdx.x * 4 + (threadIdx.x >> 6);
  const int lane = threadIdx.x & 63;
  if (n >= N_NODES) return;
  const int beg = offsets[n], end = offsets[n + 1];
  const int h = lane >> 4;
  const int c0 = lane * 8;
  const float aldh = ald[n * 4 + h];
  float m = -1e30f;
  for (int p = beg; p < end; p++)
    m = fmaxf(m, leaky(als[srcs[p] * 4 + h] + aldh));
  float den = 0.f;
  float acc[8] = {0, 0, 0, 0, 0, 0, 0, 0};
  for (int p = beg; p < end; p++) {
    const int s = srcs[p];
    const float w = __expf(leaky(als[s * 4 + h] + aldh) - m);
    den += w;
    const bf16x8 hv = *(const bf16x8*)&h1b[(size_t)s * 512 + c0];
#pragma unroll
    for (int j = 0; j < 8; j++) acc[j] += w * bf2f(hv[j]);
  }
  bf16x8 o;
  const float inv = 1.f / den;
#pragma unroll
  for (int j = 0; j < 8; j++)
    o[j] = (short)f2bf(fmaxf(acc[j] * inv + b1[c0 + j], 0.f));
  *(bf16x8*)&x2b[(size_t)n * 512 + c0] = o;
}

// ---------------- GAT aggregation layer 2 (h2 fp32; lane owns 2 contiguous ch) ----------------
__global__ __launch_bounds__(256) void aggregate2(const float* __restrict__ h2,
                                                  const float* __restrict__ als,
                                                  const float* __restrict__ ald,
                                                  const int* __restrict__ offsets,
                                                  const int* __restrict__ srcs,
                                                  const float* __restrict__ b2,
                                                  float* __restrict__ out2) {
  const int n = blockIdx.x * 4 + (threadIdx.x >> 6);
  const int lane = threadIdx.x & 63;
  if (n >= N_NODES) return;
  const int beg = offsets[n], end = offsets[n + 1];
  const int c0 = lane * 2;
  const float aldn = ald[n];
  float m = -1e30f;
  for (int p = beg; p < end; p++) m = fmaxf(m, leaky(als[srcs[p]] + aldn));
  float den = 0.f, a0 = 0.f, a1 = 0.f;
  for (int p = beg; p < end; p++) {
    const int s = srcs[p];
    const float w = __expf(leaky(als[s] + aldn) - m);
    den += w;
    const float2 hv = *(const float2*)&h2[(size_t)s * 128 + c0];
    a0 += w * hv.x;
    a1 += w * hv.y;
  }
  const float inv = 1.f / den;
  float2 o = make_float2(fmaxf(a0 * inv + b2[c0], 0.f), fmaxf(a1 * inv + b2[c0 + 1], 0.f));
  *(float2*)&out2[(size_t)n * 128 + c0] = o;
}

// ---------------- global mean pool (batch sorted -> run-length accumulate) ----------------
__global__ __launch_bounds__(128) void pool_kernel(const float* __restrict__ out2,
                                                   const int* __restrict__ batch,
                                                   float* pooled, float* cnts) {
  const int t = threadIdx.x;
  const int base = blockIdx.x * 256;
  float acc = 0.f;
  float cnt = 0.f;
  int cur = -1;
  for (int i = 0; i < 256; i++) {
    const int n = base + i;
    if (n >= N_NODES) break;
    const int g = batch[n];
    if (g != cur) {
      if (cur >= 0) {
        atomicAdd(&pooled[cur * HID + t], acc);
        if (t == 0) atomicAdd(&cnts[cur], cnt);
      }
      acc = 0.f; cnt = 0.f; cur = g;
    }
    acc += out2[(size_t)n * HID + t];
    cnt += 1.f;
  }
  if (cur >= 0) {
    atomicAdd(&pooled[cur * HID + t], acc);
    if (t == 0) atomicAdd(&cnts[cur], cnt);
  }
}

// ---------------- MLP head ----------------
__global__ __launch_bounds__(64) void mlp_kernel(const float* __restrict__ pooled,
                                                 const float* __restrict__ cnts,
                                                 const float* __restrict__ fc1_w,
                                                 const float* __restrict__ fc1_b,
                                                 const float* __restrict__ fc2_w,
                                                 const float* __restrict__ fc2_b,
                                                 float* __restrict__ out) {
  __shared__ float pl[128];
  __shared__ float z[64];
  const int g = blockIdx.x, t = threadIdx.x;
  const float c = fmaxf(cnts[g], 1.0f);
  pl[t] = pooled[g * HID + t] / c;
  pl[t + 64] = pooled[g * HID + t + 64] / c;
  __syncthreads();
  float acc = fc1_b[t];
  for (int i = 0; i < 128; i++) acc += pl[i] * fc1_w[i * 64 + t];
  z[t] = fmaxf(acc, 0.f);
  __syncthreads();
  if (t < NUM_CLASSES) {
    float o = fc2_b[t];
    for (int i = 0; i < 64; i++) o += z[i] * fc2_w[i * NUM_CLASSES + t];
    out[g * NUM_CLASSES + t] = o;
  }
}

extern "C" void kernel_launch(void* const* d_in, const int* in_sizes, int n_in,
                              void* d_out, int out_size, void* d_ws, size_t ws_size,
                              hipStream_t stream) {
  const float* x       = (const float*)d_in[0];
  const int*   ei      = (const int*)d_in[1];
  const int*   batch   = (const int*)d_in[2];
  const float* W1      = (const float*)d_in[3];
  const float* a_src1  = (const float*)d_in[4];
  const float* a_dst1  = (const float*)d_in[5];
  const float* b1      = (const float*)d_in[6];
  const float* W2      = (const float*)d_in[7];
  const float* a_src2  = (const float*)d_in[8];
  const float* a_dst2  = (const float*)d_in[9];
  const float* b2      = (const float*)d_in[10];
  const float* fc1_w   = (const float*)d_in[11];
  const float* fc1_b   = (const float*)d_in[12];
  const float* fc2_w   = (const float*)d_in[13];
  const float* fc2_b   = (const float*)d_in[14];
  float* out = (float*)d_out;

  const int* e_src = ei;
  const int* e_dst = ei + N_EDGES;

  // workspace layout (units: floats from d_ws base)
  float* wsf = (float*)d_ws;
  unsigned short* h1b = (unsigned short*)wsf;              // 50000*512 bf16 = 12.8M floats
  unsigned short* Ab  = (unsigned short*)(wsf + 12800000); // 50000*832 bf16 = 20.8M floats
  unsigned short* x2b = (unsigned short*)(wsf + 33600000); // 50000*512 bf16 = 12.8M floats
  unsigned short* Bt  = (unsigned short*)(wsf + 46400000); // 512*832 bf16 = 212,992 floats
  unsigned short* Bt2 = (unsigned short*)(wsf + 46613000); // 128*512 bf16 = 32,768 floats
  float* als1 = wsf + 46646000;               // 200,000
  float* ald1 = als1 + 200000;                // 200,000
  float* als2 = ald1 + 200000;                // 50,000
  float* ald2 = als2 + 50000;                 // 50,000
  float* pooled = ald2 + 50000;               // 8,192
  float* cnts = pooled + 8192;                // 64
  int* deg     = (int*)(cnts + 64);           // 50,000
  int* offsets = deg + 50000;                 // 50,001
  int* cursor  = offsets + 50001;             // 50,000
  int* srcs    = cursor + 50000;              // 450,000
  int* bsum    = srcs + 450000;               // 196
  int* bbase   = bsum + 200;                  // 196
  // overlays into Ab region (Ab dead after gemm1):
  float* h2   = wsf + 12800000;               // 6.4M floats
  float* out2 = wsf + 19200000;               // 6.4M floats

  const int NB = (N_NODES + 255) / 256;  // 196

  // CSR build + inits
  init_misc<<<NB, 256, 0, stream>>>(deg, pooled, cnts);
  hist_kernel<<<(N_EDGES + 255) / 256, 256, 0, stream>>>(e_dst, deg);
  scan_block_sum<<<NB, 256, 0, stream>>>(deg, bsum);
  scan_base<<<1, 256, 0, stream>>>(bsum, bbase, offsets);
  scan_final<<<NB, 256, 0, stream>>>(deg, bbase, offsets, cursor);
  scatter_kernel<<<(N_EDGES + N_NODES + 255) / 256, 256, 0, stream>>>(e_src, e_dst, cursor, srcs);

  // layer 1: bf16 conversion + MFMA GEMM (h1 bf16)
  convert_x<<<N_NODES, 256, 0, stream>>>(x, Ab);
  convert_w1t<<<512, 256, 0, stream>>>(W1, Bt);
  gemm_mfma<KP, 512, true><<<dim3(391, 4), 256, 0, stream>>>(Ab, Bt, (void*)h1b);
  attn_prep1<<<12500, 256, 0, stream>>>(h1b, a_src1, a_dst1, als1, ald1);
  aggregate1<<<12500, 256, 0, stream>>>(h1b, als1, ald1, offsets, srcs, b1, x2b);

  // layer 2: bf16 MFMA GEMM (h2 fp32)
  convert_w2t<<<128, 256, 0, stream>>>(W2, Bt2);
  gemm_mfma<512, 128, false><<<dim3(391, 1), 256, 0, stream>>>(x2b, Bt2, (void*)h2);
  attn_prep2<<<12500, 256, 0, stream>>>(h2, a_src2, a_dst2, als2, ald2);
  aggregate2<<<12500, 256, 0, stream>>>(h2, als2, ald2, offsets, srcs, b2, out2);

  // pool + MLP
  pool_kernel<<<NB, 128, 0, stream>>>(out2, batch, pooled, cnts);
  mlp_kernel<<<NUM_GRAPHS, 64, 0, stream>>>(pooled, cnts, fc1_w, fc1_b, fc2_w, fc2_b, out);
}